// Round 1
// baseline (661.008 us; speedup 1.0000x reference)
//
#include <hip/hip_runtime.h>
#include <hip/hip_fp16.h>

// Problem constants (fixed by reference)
#define N_PTS 1048576
#define BSEG  2048
#define XSTR  104   // x-tile row stride in halfs: 96 K + pad -> 208 B = 13*16 (conflict-free b128)
#define HSTR  136   // h-tile row stride in halfs: 128 K + pad -> 272 B = 17*16

typedef _Float16 half8 __attribute__((ext_vector_type(8)));
typedef float floatx4 __attribute__((ext_vector_type(4)));

// ---------------------------------------------------------------------------
// Kernel W: transpose + f16-convert the three heavy-layer weights into ws.
// w1 [96][128] -> w1T [128][104] (K-padded), w2/w3 [128][128] -> [128][136].
// ---------------------------------------------------------------------------
__global__ __launch_bounds__(256) void wconv(const float* __restrict__ w1,
                                             const float* __restrict__ w2,
                                             const float* __restrict__ w3,
                                             _Float16* __restrict__ w1T,
                                             _Float16* __restrict__ w2T,
                                             _Float16* __restrict__ w3T) {
    int idx = blockIdx.x * 256 + threadIdx.x;
    if (idx < 13312) {                       // 128*104
        int j = idx / 104, k = idx % 104;
        w1T[idx] = (_Float16)((k < 96) ? w1[k * 128 + j] : 0.f);
    } else if (idx < 13312 + 17408) {        // 128*136
        int i = idx - 13312;
        int j = i / 136, k = i % 136;
        w2T[i] = (_Float16)((k < 128) ? w2[k * 128 + j] : 0.f);
    } else if (idx < 13312 + 2 * 17408) {
        int i = idx - 13312 - 17408;
        int j = i / 136, k = i % 136;
        w3T[i] = (_Float16)((k < 128) ? w3[k * 128 + j] : 0.f);
    }
}

// ---------------------------------------------------------------------------
// Kernel A: per-segment neighborhood encoder + segment max.
// One block per segment; fp32 exact. relu>=0 so init-0 max == reference's
// neginf->0 guard (incl. empty segments).
// ---------------------------------------------------------------------------
__global__ __launch_bounds__(256) void enc_pool(const float* __restrict__ pts,
                                                const int* __restrict__ batch,
                                                const float* __restrict__ wne,
                                                const float* __restrict__ bne,
                                                float* __restrict__ relenc) {
    const int b = blockIdx.x, tid = threadIdx.x;
    __shared__ float swne[96];
    __shared__ float sbne[32];
    __shared__ float red[4][32];
    if (tid < 96) swne[tid] = wne[tid];
    if (tid < 32) sbne[tid] = bne[tid];

    // segment range via binary search (batch sorted, uniform per block)
    int lo = 0, hi = N_PTS;
    while (lo < hi) { int mid = (lo + hi) >> 1; if (batch[mid] < b) lo = mid + 1; else hi = mid; }
    const int start = lo;
    hi = N_PTS;
    while (lo < hi) { int mid = (lo + hi) >> 1; if (batch[mid] < b + 1) lo = mid + 1; else hi = mid; }
    const int end = lo;
    __syncthreads();

    float mx[32];
#pragma unroll
    for (int j = 0; j < 32; j++) mx[j] = 0.f;

    for (int p = start + tid; p < end; p += 256) {
        // RADIUS == 1.0 -> points/RADIUS is a no-op
        float x0 = pts[3 * p], x1 = pts[3 * p + 1], x2 = pts[3 * p + 2];
#pragma unroll
        for (int j = 0; j < 32; j++) {
            float e = fmaf(x0, swne[j], fmaf(x1, swne[32 + j], fmaf(x2, swne[64 + j], sbne[j])));
            mx[j] = fmaxf(mx[j], e);   // relu folded into max(0-init)
        }
    }
#pragma unroll
    for (int j = 0; j < 32; j++) {
#pragma unroll
        for (int off = 1; off < 64; off <<= 1)
            mx[j] = fmaxf(mx[j], __shfl_xor(mx[j], off, 64));
    }
    const int wv = tid >> 6;
    if ((tid & 63) == 0) {
#pragma unroll
        for (int j = 0; j < 32; j++) red[wv][j] = mx[j];
    }
    __syncthreads();
    if (tid < 32) {
        float v = fmaxf(fmaxf(red[0][tid], red[1][tid]), fmaxf(red[2][tid], red[3][tid]));
        relenc[b * 32 + tid] = v;
    }
}

// ---------------------------------------------------------------------------
// Kernel B: per-segment fused 3-layer MLP (f16 MFMA) + segment max + fp32 head.
// 512 threads = 8 waves: wave = (mtile in 0..3) x (jhalf in 0..1).
// Each wave: 16-point M-tile x 4 j-tiles (64 outs); B-frags VGPR-resident.
// LDS: x ping/pong 26.6K + h1/h2 34.8K + head scratch < 64K.
// ---------------------------------------------------------------------------
__global__ __launch_bounds__(512, 2) void fused_mlp(
    const float* __restrict__ feat, const int* __restrict__ batch,
    const float* __restrict__ relenc,
    const _Float16* __restrict__ w1T, const _Float16* __restrict__ w2T,
    const _Float16* __restrict__ w3T,
    const float* __restrict__ b1, const float* __restrict__ b2, const float* __restrict__ b3,
    const float* __restrict__ wg1, const float* __restrict__ bg1,
    const float* __restrict__ wg2, const float* __restrict__ bg2,
    const float* __restrict__ wg3, const float* __restrict__ bg3,
    float* __restrict__ out) {
    __shared__ __attribute__((aligned(16))) _Float16 xb[2][64 * XSTR];
    __shared__ __attribute__((aligned(16))) _Float16 h1[64 * HSTR];
    __shared__ __attribute__((aligned(16))) _Float16 h2[64 * HSTR];
    __shared__ int pooledi[128];
    __shared__ float g1s[128];
    __shared__ float g2s[64];

    const int b = blockIdx.x, tid = threadIdx.x;
    const int lane = tid & 63, wid = tid >> 6;
    const int mtile = wid & 3, jhalf = wid >> 2;
    const int l15 = lane & 15, quad = lane >> 4;

    // segment range
    int lo = 0, hi = N_PTS;
    while (lo < hi) { int mid = (lo + hi) >> 1; if (batch[mid] < b) lo = mid + 1; else hi = mid; }
    const int start = lo;
    hi = N_PTS;
    while (lo < hi) { int mid = (lo + hi) >> 1; if (batch[mid] < b + 1) lo = mid + 1; else hi = mid; }
    const int end = lo;
    const int n = end - start;
    const int niter = (n + 63) >> 6;

    if (tid < 128) pooledi[tid] = 0;

    // broadcast rel_encoded row into cols 0..31 of both x buffers (all rows)
    {
        int col = tid & 31;
        _Float16 hv = (_Float16)relenc[b * 32 + col];
        int r0 = tid >> 5;  // 0..15
#pragma unroll
        for (int rr = 0; rr < 64; rr += 16) {
            xb[0][(r0 + rr) * XSTR + col] = hv;
            xb[1][(r0 + rr) * XSTR + col] = hv;
        }
    }

    // B-fragments, VGPR-resident for the whole kernel.
    // frag layout (m89-verified): elem t of lane L = Wt[n = (L&15)][k = ks*32 + (L>>4)*8 + t]
    half8 w1f[4][3], w2f[4][4], w3f[4][4];
    {
        const int jb = jhalf * 64 + l15;
#pragma unroll
        for (int jt = 0; jt < 4; jt++) {
            int jj = jb + jt * 16;
#pragma unroll
            for (int ks = 0; ks < 3; ks++)
                w1f[jt][ks] = *(const half8*)(w1T + jj * XSTR + ks * 32 + quad * 8);
#pragma unroll
            for (int ks = 0; ks < 4; ks++) {
                w2f[jt][ks] = *(const half8*)(w2T + jj * HSTR + ks * 32 + quad * 8);
                w3f[jt][ks] = *(const half8*)(w3T + jj * HSTR + ks * 32 + quad * 8);
            }
        }
    }
    float bb1[4], bb2[4], bb3[4];
#pragma unroll
    for (int jt = 0; jt < 4; jt++) {
        int jj = jhalf * 64 + jt * 16 + l15;
        bb1[jt] = b1[jj]; bb2[jt] = b2[jj]; bb3[jt] = b3[jj];
    }

    // feature staging: 1024 float4 tasks/tile, 2 per thread; double-buffered
    floatx4 pf[2];
    auto issue = [&](int it) {
#pragma unroll
        for (int u = 0; u < 2; u++) {
            int t = tid + u * 512;
            int row = t >> 4, c4 = t & 15;
            int p = start + it * 64 + row;
            if (p < end) pf[u] = *(const floatx4*)(feat + (size_t)p * 64 + c4 * 4);
            else         pf[u] = (floatx4){0.f, 0.f, 0.f, 0.f};
        }
    };
    auto commit = [&](int buf) {
#pragma unroll
        for (int u = 0; u < 2; u++) {
            int t = tid + u * 512;
            int row = t >> 4, c4 = t & 15;
            _Float16* d = &xb[buf][row * XSTR + 32 + c4 * 4];
            d[0] = (_Float16)pf[u][0]; d[1] = (_Float16)pf[u][1];
            d[2] = (_Float16)pf[u][2]; d[3] = (_Float16)pf[u][3];
        }
    };
    if (niter > 0) { issue(0); commit(0); }
    __syncthreads();

    floatx4 vmax[4];
#pragma unroll
    for (int jt = 0; jt < 4; jt++) vmax[jt] = (floatx4){0.f, 0.f, 0.f, 0.f};

    for (int it = 0; it < niter; it++) {
        const int buf = it & 1;
        const bool havenext = (it + 1) < niter;
        if (havenext) issue(it + 1);          // loads in flight across all 3 layers

        floatx4 acc[4];
        // ---- Layer 1: x[buf] (K=96) -> h1 ----
#pragma unroll
        for (int jt = 0; jt < 4; jt++) acc[jt] = (floatx4){0.f, 0.f, 0.f, 0.f};
#pragma unroll
        for (int ks = 0; ks < 3; ks++) {
            half8 a = *(const half8*)(&xb[buf][(mtile * 16 + l15) * XSTR + ks * 32 + quad * 8]);
#pragma unroll
            for (int jt = 0; jt < 4; jt++)
                acc[jt] = __builtin_amdgcn_mfma_f32_16x16x32_f16(a, w1f[jt][ks], acc[jt], 0, 0, 0);
        }
#pragma unroll
        for (int jt = 0; jt < 4; jt++) {
            int jj = jhalf * 64 + jt * 16 + l15;
#pragma unroll
            for (int r = 0; r < 4; r++) {
                float v = fmaxf(acc[jt][r] + bb1[jt], 0.f);
                h1[(mtile * 16 + quad * 4 + r) * HSTR + jj] = (_Float16)v;   // D: row=quad*4+reg, col=lane&15
            }
        }
        __syncthreads();

        // ---- Layer 2: h1 (K=128) -> h2 ----
#pragma unroll
        for (int jt = 0; jt < 4; jt++) acc[jt] = (floatx4){0.f, 0.f, 0.f, 0.f};
#pragma unroll
        for (int ks = 0; ks < 4; ks++) {
            half8 a = *(const half8*)(&h1[(mtile * 16 + l15) * HSTR + ks * 32 + quad * 8]);
#pragma unroll
            for (int jt = 0; jt < 4; jt++)
                acc[jt] = __builtin_amdgcn_mfma_f32_16x16x32_f16(a, w2f[jt][ks], acc[jt], 0, 0, 0);
        }
#pragma unroll
        for (int jt = 0; jt < 4; jt++) {
            int jj = jhalf * 64 + jt * 16 + l15;
#pragma unroll
            for (int r = 0; r < 4; r++) {
                float v = fmaxf(acc[jt][r] + bb2[jt], 0.f);
                h2[(mtile * 16 + quad * 4 + r) * HSTR + jj] = (_Float16)v;
            }
        }
        __syncthreads();

        // ---- Layer 3: h2 (K=128) -> vmax (registers; tail rows masked to 0) ----
#pragma unroll
        for (int jt = 0; jt < 4; jt++) acc[jt] = (floatx4){0.f, 0.f, 0.f, 0.f};
#pragma unroll
        for (int ks = 0; ks < 4; ks++) {
            half8 a = *(const half8*)(&h2[(mtile * 16 + l15) * HSTR + ks * 32 + quad * 8]);
#pragma unroll
            for (int jt = 0; jt < 4; jt++)
                acc[jt] = __builtin_amdgcn_mfma_f32_16x16x32_f16(a, w3f[jt][ks], acc[jt], 0, 0, 0);
        }
#pragma unroll
        for (int jt = 0; jt < 4; jt++) {
#pragma unroll
            for (int r = 0; r < 4; r++) {
                int row = mtile * 16 + quad * 4 + r;
                float v = ((it * 64 + row) < n) ? fmaxf(acc[jt][r] + bb3[jt], 0.f) : 0.f;
                vmax[jt][r] = fmaxf(vmax[jt][r], v);
            }
        }
        if (havenext) commit(buf ^ 1);
        __syncthreads();
    }

    // reduce vmax: 4 rows in-lane, then across quads; combine M-tiles via LDS atomic
#pragma unroll
    for (int jt = 0; jt < 4; jt++) {
        float m = fmaxf(fmaxf(vmax[jt][0], vmax[jt][1]), fmaxf(vmax[jt][2], vmax[jt][3]));
        m = fmaxf(m, __shfl_xor(m, 16, 64));
        m = fmaxf(m, __shfl_xor(m, 32, 64));
        if (quad == 0)
            atomicMax(&pooledi[jhalf * 64 + jt * 16 + l15], __float_as_int(m));  // vals >= 0
    }
    __syncthreads();

    // ---- fp32 head MLP (tiny) ----
    if (tid < 128) {
        float acc = bg1[tid];
#pragma unroll 8
        for (int k = 0; k < 128; k++) acc = fmaf(__int_as_float(pooledi[k]), wg1[k * 128 + tid], acc);
        g1s[tid] = fmaxf(acc, 0.f);
    }
    __syncthreads();
    if (tid < 64) {
        float acc = bg2[tid];
#pragma unroll 8
        for (int k = 0; k < 128; k++) acc = fmaf(g1s[k], wg2[k * 64 + tid], acc);
        g2s[tid] = fmaxf(acc, 0.f);
    }
    __syncthreads();
    if (tid < 32) {
        float acc = bg3[tid];
#pragma unroll 8
        for (int k = 0; k < 64; k++) acc = fmaf(g2s[k], wg3[k * 32 + tid], acc);
        out[b * 32 + tid] = fmaxf(acc, 0.f);
    }
}

// ---------------------------------------------------------------------------
extern "C" void kernel_launch(void* const* d_in, const int* in_sizes, int n_in,
                              void* d_out, int out_size, void* d_ws, size_t ws_size,
                              hipStream_t stream) {
    const float* points = (const float*)d_in[0];
    const float* feat   = (const float*)d_in[1];
    const int*   batch  = (const int*)d_in[2];
    const float* w_ne   = (const float*)d_in[3];
    const float* b_ne   = (const float*)d_in[4];
    const float* w1  = (const float*)d_in[5];
    const float* b1  = (const float*)d_in[6];
    const float* w2  = (const float*)d_in[7];
    const float* b2  = (const float*)d_in[8];
    const float* w3  = (const float*)d_in[9];
    const float* b3  = (const float*)d_in[10];
    const float* wg1 = (const float*)d_in[11];
    const float* bg1 = (const float*)d_in[12];
    const float* wg2 = (const float*)d_in[13];
    const float* bg2 = (const float*)d_in[14];
    const float* wg3 = (const float*)d_in[15];
    const float* bg3 = (const float*)d_in[16];
    float* out = (float*)d_out;

    char* ws = (char*)d_ws;
    float*    relenc = (float*)ws;                      // 2048*32 f32 = 262144 B
    _Float16* w1T = (_Float16*)(ws + 262144);           // 13312 halfs = 26624 B
    _Float16* w2T = (_Float16*)(ws + 262144 + 26624);   // 17408 halfs = 34816 B
    _Float16* w3T = (_Float16*)(ws + 262144 + 26624 + 34816);

    wconv<<<188, 256, 0, stream>>>(w1, w2, w3, w1T, w2T, w3T);
    enc_pool<<<BSEG, 256, 0, stream>>>(points, batch, w_ne, b_ne, relenc);
    fused_mlp<<<BSEG, 512, 0, stream>>>(feat, batch, relenc, w1T, w2T, w3T,
                                        b1, b2, b3, wg1, bg1, wg2, bg2, wg3, bg3, out);
}

// Round 2
// 555.848 us; speedup vs baseline: 1.1892x; 1.1892x over previous
//
#include <hip/hip_runtime.h>
#include <hip/hip_fp16.h>

// Problem constants (fixed by reference)
#define N_PTS 1048576
#define BSEG  2048
#define XSTR  72    // xfeat f16 row stride: 64 features + 8 pad (144 B, 16B-aligned, bank-spread)

typedef _Float16 half8  __attribute__((ext_vector_type(8)));
typedef _Float16 half4  __attribute__((ext_vector_type(4)));
typedef _Float16 half2v __attribute__((ext_vector_type(2)));
typedef float    floatx4 __attribute__((ext_vector_type(4)));

// ---------------------------------------------------------------------------
// Kernel W: transpose + f16-convert heavy-layer weights.
// Reference concat order is [enc(32) | feat(64)], so w1 rows 32..95 are the
// feature part -> w1T [128 j][64 k]. Rows 0..31 (enc part) are folded into a
// per-segment bias by enc_pool. w2/w3 -> [128 j][128 k].
// ---------------------------------------------------------------------------
__global__ __launch_bounds__(256) void wconv(const float* __restrict__ w1,
                                             const float* __restrict__ w2,
                                             const float* __restrict__ w3,
                                             _Float16* __restrict__ w1T,
                                             _Float16* __restrict__ w2T,
                                             _Float16* __restrict__ w3T) {
    int idx = blockIdx.x * 256 + threadIdx.x;
    if (idx < 8192) {                         // 128*64
        int j = idx >> 6, k = idx & 63;
        w1T[idx] = (_Float16)w1[(32 + k) * 128 + j];
    } else if (idx < 8192 + 16384) {
        int i = idx - 8192; int j = i >> 7, k = i & 127;
        w2T[i] = (_Float16)w2[k * 128 + j];
    } else if (idx < 8192 + 32768) {
        int i = idx - 8192 - 16384; int j = i >> 7, k = i & 127;
        w3T[i] = (_Float16)w3[k * 128 + j];
    }
}

// ---------------------------------------------------------------------------
// Kernel A: per-segment encoder + segment-max + fold enc through W1's enc rows
// into a per-segment bias b1p[b][128] = b1 + enc . W1[0:32,:]  (fp32 exact).
// relu>=0 so init-0 max == reference's neginf->0 guard (incl. empty segments).
// ---------------------------------------------------------------------------
__global__ __launch_bounds__(256) void enc_pool(const float* __restrict__ pts,
                                                const int* __restrict__ batch,
                                                const float* __restrict__ wne,
                                                const float* __restrict__ bne,
                                                const float* __restrict__ w1,
                                                const float* __restrict__ b1,
                                                float* __restrict__ b1p) {
    const int b = blockIdx.x, tid = threadIdx.x;
    __shared__ float swne[96];
    __shared__ float sbne[32];
    __shared__ float red[4][32];
    __shared__ float sEnc[32];
    if (tid < 96) swne[tid] = wne[tid];
    if (tid < 32) sbne[tid] = bne[tid];

    int lo = 0, hi = N_PTS;
    while (lo < hi) { int mid = (lo + hi) >> 1; if (batch[mid] < b) lo = mid + 1; else hi = mid; }
    const int start = lo;
    hi = N_PTS;
    while (lo < hi) { int mid = (lo + hi) >> 1; if (batch[mid] < b + 1) lo = mid + 1; else hi = mid; }
    const int end = lo;
    __syncthreads();

    float mx[32];
#pragma unroll
    for (int j = 0; j < 32; j++) mx[j] = 0.f;
    for (int p = start + tid; p < end; p += 256) {
        float x0 = pts[3 * p], x1 = pts[3 * p + 1], x2 = pts[3 * p + 2];
#pragma unroll
        for (int j = 0; j < 32; j++) {
            float e = fmaf(x0, swne[j], fmaf(x1, swne[32 + j], fmaf(x2, swne[64 + j], sbne[j])));
            mx[j] = fmaxf(mx[j], e);
        }
    }
#pragma unroll
    for (int j = 0; j < 32; j++) {
#pragma unroll
        for (int off = 1; off < 64; off <<= 1)
            mx[j] = fmaxf(mx[j], __shfl_xor(mx[j], off, 64));
    }
    const int wv = tid >> 6;
    if ((tid & 63) == 0) {
#pragma unroll
        for (int j = 0; j < 32; j++) red[wv][j] = mx[j];
    }
    __syncthreads();
    if (tid < 32)
        sEnc[tid] = fmaxf(fmaxf(red[0][tid], red[1][tid]), fmaxf(red[2][tid], red[3][tid]));
    __syncthreads();
    if (tid < 128) {
        float acc = b1[tid];
#pragma unroll 8
        for (int k = 0; k < 32; k++) acc = fmaf(sEnc[k], w1[k * 128 + tid], acc);
        b1p[b * 128 + tid] = acc;
    }
}

// ---------------------------------------------------------------------------
// Kernel B: per-segment fused 3-layer MLP (f16 MFMA) + segment max + fp32 head.
// 256 threads = 4 waves. Each wave owns 32 output cols (jsplit=4) for the
// iteration's 16 rows (msplit=1). B-frags VGPR-resident: 80 regs/wave.
// h tiles in LDS with XOR chunk-swizzle (conflict-free writes via DPP-paired
// half2 stores). 2 barriers/iter. LDS ~14 KB -> 4 blocks/CU at 4 waves/EU.
// ---------------------------------------------------------------------------
__global__ __launch_bounds__(256, 4) void fused_mlp(
    const float* __restrict__ feat, const int* __restrict__ batch,
    const float* __restrict__ b1p_g,
    const _Float16* __restrict__ w1T, const _Float16* __restrict__ w2T,
    const _Float16* __restrict__ w3T,
    const float* __restrict__ b2, const float* __restrict__ b3,
    const float* __restrict__ wg1, const float* __restrict__ bg1,
    const float* __restrict__ wg2, const float* __restrict__ bg2,
    const float* __restrict__ wg3, const float* __restrict__ bg3,
    float* __restrict__ out) {
    __shared__ __attribute__((aligned(16))) _Float16 xf[2][16 * XSTR];  // 4.6 KB
    __shared__ __attribute__((aligned(16))) _Float16 h1s[16 * 128];     // 4 KB, swizzled
    __shared__ __attribute__((aligned(16))) _Float16 h2s[16 * 128];     // 4 KB, swizzled
    __shared__ float pooled[128];
    __shared__ float g1s[128];
    __shared__ float g2s[64];

    const int b = blockIdx.x, tid = threadIdx.x;
    const int lane = tid & 63, jq = tid >> 6;
    const int l15 = lane & 15, quad = lane >> 4;
    const int podd = l15 & 1;

    // segment range (batch sorted)
    int lo = 0, hi = N_PTS;
    while (lo < hi) { int mid = (lo + hi) >> 1; if (batch[mid] < b) lo = mid + 1; else hi = mid; }
    const int start = lo;
    hi = N_PTS;
    while (lo < hi) { int mid = (lo + hi) >> 1; if (batch[mid] < b + 1) lo = mid + 1; else hi = mid; }
    const int end = lo;
    const int n = end - start;
    const int niter = (n + 15) >> 4;

    if (tid < 128) pooled[tid] = 0.f;

    // B-fragments (weights), VGPR-resident: 20 half8 = 80 VGPRs.
    // frag layout: elem t of lane = W[n = jcol][k = ks*32 + quad*8 + t]
    const int jc0 = jq * 32 + l15, jc1 = jc0 + 16;
    half8 w1f[2][2], w2f[2][4], w3f[2][4];
#pragma unroll
    for (int ks = 0; ks < 2; ks++) {
        w1f[0][ks] = *(const half8*)(w1T + jc0 * 64 + ks * 32 + quad * 8);
        w1f[1][ks] = *(const half8*)(w1T + jc1 * 64 + ks * 32 + quad * 8);
    }
#pragma unroll
    for (int ks = 0; ks < 4; ks++) {
        w2f[0][ks] = *(const half8*)(w2T + jc0 * 128 + ks * 32 + quad * 8);
        w2f[1][ks] = *(const half8*)(w2T + jc1 * 128 + ks * 32 + quad * 8);
        w3f[0][ks] = *(const half8*)(w3T + jc0 * 128 + ks * 32 + quad * 8);
        w3f[1][ks] = *(const half8*)(w3T + jc1 * 128 + ks * 32 + quad * 8);
    }
    float bb1[2], bb2[2], bb3[2];
    bb1[0] = b1p_g[b * 128 + jc0]; bb1[1] = b1p_g[b * 128 + jc1];
    bb2[0] = b2[jc0]; bb2[1] = b2[jc1];
    bb3[0] = b3[jc0]; bb3[1] = b3[jc1];

    // staging: 1 float4/thread/iter (16 rows x 64 f32)
    const int srow = tid >> 4, scol = tid & 15;
    floatx4 pf;
    auto issue = [&](int it) {
        int p = start + it * 16 + srow;
        if (p < end) pf = *(const floatx4*)(feat + (size_t)p * 64 + scol * 4);
        else         pf = (floatx4){0.f, 0.f, 0.f, 0.f};
    };
    auto commit = [&](int buf) {
        half4 hv = {(_Float16)pf.x, (_Float16)pf.y, (_Float16)pf.z, (_Float16)pf.w};
        *(half4*)(&xf[buf][srow * XSTR + scol * 4]) = hv;
    };
    // pack 2 rows x 2 cols per lane via DPP xor-1, write half2 (conflict-free)
    auto storeH = [&](_Float16* hbuf, floatx4* acc, float* bb) {
#pragma unroll
        for (int jt = 0; jt < 2; jt++) {
            float v0 = fmaxf(acc[jt][0] + bb[jt], 0.f);
            float v1 = fmaxf(acc[jt][1] + bb[jt], 0.f);
            float v2 = fmaxf(acc[jt][2] + bb[jt], 0.f);
            float v3 = fmaxf(acc[jt][3] + bb[jt], 0.f);
            float s0 = podd ? v0 : v2;          // send what partner needs
            float s1 = podd ? v1 : v3;
            s0 = __shfl_xor(s0, 1, 64);
            s1 = __shfl_xor(s1, 1, 64);
            float lo0 = podd ? s0 : v0, hi0 = podd ? v2 : s0;
            float lo1 = podd ? s1 : v1, hi1 = podd ? v3 : s1;
            int r0 = quad * 4 + (podd ? 2 : 0);
            int c0 = jq * 32 + jt * 16 + (l15 & ~1);
            int off0 = r0 * 128 + ((((c0 >> 3) ^ r0) & 15) << 3) + (c0 & 7);
            int r1 = r0 + 1;
            int off1 = r1 * 128 + ((((c0 >> 3) ^ r1) & 15) << 3) + (c0 & 7);
            *(half2v*)(&hbuf[off0]) = (half2v){(_Float16)lo0, (_Float16)hi0};
            *(half2v*)(&hbuf[off1]) = (half2v){(_Float16)lo1, (_Float16)hi1};
        }
    };

    if (niter > 0) { issue(0); commit(0); if (niter > 1) issue(1); }
    __syncthreads();

    float vmax[2] = {0.f, 0.f};

    for (int it = 0; it < niter; it++) {
        const int buf = it & 1;
        floatx4 acc[2];

        // ---- Layer 1: xf[buf] (K=64) ----
        acc[0] = (floatx4){0.f, 0.f, 0.f, 0.f};
        acc[1] = (floatx4){0.f, 0.f, 0.f, 0.f};
#pragma unroll
        for (int ks = 0; ks < 2; ks++) {
            half8 a = *(const half8*)(&xf[buf][l15 * XSTR + ks * 32 + quad * 8]);
            acc[0] = __builtin_amdgcn_mfma_f32_16x16x32_f16(a, w1f[0][ks], acc[0], 0, 0, 0);
            acc[1] = __builtin_amdgcn_mfma_f32_16x16x32_f16(a, w1f[1][ks], acc[1], 0, 0, 0);
        }
        storeH(h1s, acc, bb1);
        __syncthreads();   // B1: h1 ready

        // ---- Layer 2: h1 (K=128) ----
        acc[0] = (floatx4){0.f, 0.f, 0.f, 0.f};
        acc[1] = (floatx4){0.f, 0.f, 0.f, 0.f};
#pragma unroll
        for (int ks = 0; ks < 4; ks++) {
            half8 a = *(const half8*)(&h1s[(l15 << 7) + ((((ks * 4 + quad) ^ l15) & 15) << 3)]);
            acc[0] = __builtin_amdgcn_mfma_f32_16x16x32_f16(a, w2f[0][ks], acc[0], 0, 0, 0);
            acc[1] = __builtin_amdgcn_mfma_f32_16x16x32_f16(a, w2f[1][ks], acc[1], 0, 0, 0);
        }
        storeH(h2s, acc, bb2);
        if (it + 1 < niter) { commit(buf ^ 1); if (it + 2 < niter) issue(it + 2); }
        __syncthreads();   // B2: h2 + next x ready

        // ---- Layer 3: h2 (K=128) -> vmax (tail rows masked) ----
        acc[0] = (floatx4){0.f, 0.f, 0.f, 0.f};
        acc[1] = (floatx4){0.f, 0.f, 0.f, 0.f};
#pragma unroll
        for (int ks = 0; ks < 4; ks++) {
            half8 a = *(const half8*)(&h2s[(l15 << 7) + ((((ks * 4 + quad) ^ l15) & 15) << 3)]);
            acc[0] = __builtin_amdgcn_mfma_f32_16x16x32_f16(a, w3f[0][ks], acc[0], 0, 0, 0);
            acc[1] = __builtin_amdgcn_mfma_f32_16x16x32_f16(a, w3f[1][ks], acc[1], 0, 0, 0);
        }
        const int rowbase = it * 16 + quad * 4;
#pragma unroll
        for (int jt = 0; jt < 2; jt++) {
#pragma unroll
            for (int r = 0; r < 4; r++) {
                float v = ((rowbase + r) < n) ? fmaxf(acc[jt][r] + bb3[jt], 0.f) : 0.f;
                vmax[jt] = fmaxf(vmax[jt], v);
            }
        }
        // no barrier: next L1 touches only h1/xf; h2 reuse fenced by next B1
    }

    // cross-quad row reduction; each col owned by exactly one wave -> plain store
#pragma unroll
    for (int jt = 0; jt < 2; jt++) {
        float m = vmax[jt];
        m = fmaxf(m, __shfl_xor(m, 16, 64));
        m = fmaxf(m, __shfl_xor(m, 32, 64));
        if (quad == 0) pooled[jq * 32 + jt * 16 + l15] = m;
    }
    __syncthreads();

    // ---- fp32 head MLP (tiny, exact) ----
    if (tid < 128) {
        float acc = bg1[tid];
#pragma unroll 8
        for (int k = 0; k < 128; k++) acc = fmaf(pooled[k], wg1[k * 128 + tid], acc);
        g1s[tid] = fmaxf(acc, 0.f);
    }
    __syncthreads();
    if (tid < 64) {
        float acc = bg2[tid];
#pragma unroll 8
        for (int k = 0; k < 128; k++) acc = fmaf(g1s[k], wg2[k * 64 + tid], acc);
        g2s[tid] = fmaxf(acc, 0.f);
    }
    __syncthreads();
    if (tid < 32) {
        float acc = bg3[tid];
#pragma unroll 8
        for (int k = 0; k < 64; k++) acc = fmaf(g2s[k], wg3[k * 32 + tid], acc);
        out[b * 32 + tid] = fmaxf(acc, 0.f);
    }
}

// ---------------------------------------------------------------------------
extern "C" void kernel_launch(void* const* d_in, const int* in_sizes, int n_in,
                              void* d_out, int out_size, void* d_ws, size_t ws_size,
                              hipStream_t stream) {
    const float* points = (const float*)d_in[0];
    const float* feat   = (const float*)d_in[1];
    const int*   batch  = (const int*)d_in[2];
    const float* w_ne   = (const float*)d_in[3];
    const float* b_ne   = (const float*)d_in[4];
    const float* w1  = (const float*)d_in[5];
    const float* b1  = (const float*)d_in[6];
    const float* w2  = (const float*)d_in[7];
    const float* b2  = (const float*)d_in[8];
    const float* w3  = (const float*)d_in[9];
    const float* b3  = (const float*)d_in[10];
    const float* wg1 = (const float*)d_in[11];
    const float* bg1 = (const float*)d_in[12];
    const float* wg2 = (const float*)d_in[13];
    const float* bg2 = (const float*)d_in[14];
    const float* wg3 = (const float*)d_in[15];
    const float* bg3 = (const float*)d_in[16];
    float* out = (float*)d_out;

    char* ws = (char*)d_ws;
    float*    b1p = (float*)ws;                          // 2048*128 f32 = 1 MiB
    _Float16* w1T = (_Float16*)(ws + 1048576);           // 8192 halfs  = 16 KiB
    _Float16* w2T = (_Float16*)(ws + 1048576 + 16384);   // 16384 halfs = 32 KiB
    _Float16* w3T = (_Float16*)(ws + 1048576 + 16384 + 32768);

    wconv<<<160, 256, 0, stream>>>(w1, w2, w3, w1T, w2T, w3T);
    enc_pool<<<BSEG, 256, 0, stream>>>(points, batch, w_ne, b_ne, w1, b1, b1p);
    fused_mlp<<<BSEG, 256, 0, stream>>>(feat, batch, b1p, w1T, w2T, w3T,
                                        b2, b3, wg1, bg1, wg2, bg2, wg3, bg3, out);
}